// Round 1
// baseline (154.804 us; speedup 1.0000x reference)
//
#include <hip/hip_runtime.h>
#include <math.h>

#define Bn 64
#define Pn 8732
#define Cn 21
#define NMAXn 50

// ---------------------------------------------------------------------------
// K1: per (b,p) find best GT (argmax over valid GTs of IoU).
// Packs result as (best_idx << 1) | (best_iou >= 0.5).
// ---------------------------------------------------------------------------
__global__ __launch_bounds__(256) void k_match(const float* __restrict__ labels,
                                               const int* __restrict__ objc,
                                               const float* __restrict__ priors,
                                               int* __restrict__ match) {
    const int b = blockIdx.y;
    const int p = blockIdx.x * 256 + threadIdx.x;
    __shared__ float lab[NMAXn * 5];
    __shared__ int cnt_s;
    for (int i = threadIdx.x; i < NMAXn * 5; i += 256) lab[i] = labels[b * NMAXn * 5 + i];
    if (threadIdx.x == 0) cnt_s = objc[b];
    __syncthreads();
    if (p >= Pn) return;
    const float4 pr = reinterpret_cast<const float4*>(priors)[p];
    const float px0 = pr.x - 0.5f * pr.z, py0 = pr.y - 0.5f * pr.w;
    const float px1 = pr.x + 0.5f * pr.z, py1 = pr.y + 0.5f * pr.w;
    const float parea = (px1 - px0) * (py1 - py0);
    const int cnt = cnt_s;
    float best = -1.0f;
    int bidx = 0;
    for (int n = 0; n < cnt; ++n) {
        const float gx0 = lab[n * 5 + 0], gy0 = lab[n * 5 + 1];
        const float gx1 = lab[n * 5 + 2], gy1 = lab[n * 5 + 3];
        const float lx = fmaxf(gx0, px0), ly = fmaxf(gy0, py0);
        const float rx = fminf(gx1, px1), ry = fminf(gy1, py1);
        const float w = fmaxf(rx - lx, 0.0f), h = fmaxf(ry - ly, 0.0f);
        const float inter = w * h;
        const float ga = (gx1 - gx0) * (gy1 - gy0);
        const float v = inter / (ga + parea - inter);
        if (v > best) { best = v; bidx = n; }  // strict > => first occurrence (argmax semantics)
    }
    match[(size_t)b * Pn + p] = (bidx << 1) | (best >= 0.5f ? 1 : 0);
}

// ---------------------------------------------------------------------------
// K2: per (b,n) find best prior (argmax over P of IoU), min-index tie-break.
// ---------------------------------------------------------------------------
__global__ __launch_bounds__(256) void k_best_prior(const float* __restrict__ labels,
                                                    const int* __restrict__ objc,
                                                    const float* __restrict__ priors,
                                                    int* __restrict__ bp) {
    const int b = blockIdx.x / NMAXn;
    const int n = blockIdx.x % NMAXn;
    if (n >= objc[b]) return;  // uniform per block
    const float gx0 = labels[(b * NMAXn + n) * 5 + 0];
    const float gy0 = labels[(b * NMAXn + n) * 5 + 1];
    const float gx1 = labels[(b * NMAXn + n) * 5 + 2];
    const float gy1 = labels[(b * NMAXn + n) * 5 + 3];
    const float ga = (gx1 - gx0) * (gy1 - gy0);
    float best = -1.0f;
    int bidx = 0;
    for (int p = threadIdx.x; p < Pn; p += 256) {
        const float4 pr = reinterpret_cast<const float4*>(priors)[p];
        const float px0 = pr.x - 0.5f * pr.z, py0 = pr.y - 0.5f * pr.w;
        const float px1 = pr.x + 0.5f * pr.z, py1 = pr.y + 0.5f * pr.w;
        const float lx = fmaxf(gx0, px0), ly = fmaxf(gy0, py0);
        const float rx = fminf(gx1, px1), ry = fminf(gy1, py1);
        const float w = fmaxf(rx - lx, 0.0f), h = fmaxf(ry - ly, 0.0f);
        const float inter = w * h;
        const float pa = (px1 - px0) * (py1 - py0);
        const float v = inter / (ga + pa - inter);
        if (v > best) { best = v; bidx = p; }  // ascending p within thread: first occurrence
    }
    __shared__ float sv[256];
    __shared__ int si[256];
    sv[threadIdx.x] = best;
    si[threadIdx.x] = bidx;
    __syncthreads();
    for (int s = 128; s > 0; s >>= 1) {
        if (threadIdx.x < s) {
            const float ov = sv[threadIdx.x + s];
            const int oi = si[threadIdx.x + s];
            if (ov > sv[threadIdx.x] || (ov == sv[threadIdx.x] && oi < si[threadIdx.x])) {
                sv[threadIdx.x] = ov;
                si[threadIdx.x] = oi;
            }
        }
        __syncthreads();
    }
    if (threadIdx.x == 0) bp[b * NMAXn + n] = si[0];
}

// ---------------------------------------------------------------------------
// K3: forced matches. Sequential per batch (1 thread/batch) so duplicate
// best-prior indices resolve "last n wins", matching scatter-in-order.
// Forced => pos flag set regardless of IoU (ovl := 2.0 >= 0.5).
// ---------------------------------------------------------------------------
__global__ void k_force(const int* __restrict__ objc, const int* __restrict__ bp,
                        int* __restrict__ match) {
    const int b = threadIdx.x;
    if (b >= Bn) return;
    const int cnt = objc[b];
    for (int n = 0; n < cnt; ++n) {
        const int p = bp[b * NMAXn + n];
        match[(size_t)b * Pn + p] = (n << 1) | 1;
    }
}

// ---------------------------------------------------------------------------
// K4: main pass. Per (b,p): lse over C=21 logits, nll = lse - logit[conf_t].
// Fused smooth-L1 for positives. Writes pos-masked mining score lc.
// Accumulates: acc[0] += smoothL1, acc[1] += pos-nll, np_b[b] += pos count.
// ---------------------------------------------------------------------------
__global__ __launch_bounds__(256) void k_main(const float* __restrict__ conf,
                                              const float* __restrict__ loc,
                                              const float* __restrict__ priors,
                                              const float* __restrict__ labels,
                                              const int* __restrict__ match,
                                              float* __restrict__ lc,
                                              int* __restrict__ np_b,
                                              float* __restrict__ acc) {
    const int b = blockIdx.y;
    const int p0 = blockIdx.x * 256;
    const int tid = threadIdx.x;
    const int rows = min(256, Pn - p0);
    __shared__ float sconf[256 * Cn];
    __shared__ float lab[NMAXn * 5];
    // rows*Cn divisible by 4 for rows in {256, 28}; base offset 16B-aligned.
    const float4* src = reinterpret_cast<const float4*>(conf + ((size_t)b * Pn + p0) * Cn);
    const int n4 = rows * Cn / 4;
    for (int i = tid; i < n4; i += 256) reinterpret_cast<float4*>(sconf)[i] = src[i];
    for (int i = tid; i < NMAXn * 5; i += 256) lab[i] = labels[b * NMAXn * 5 + i];
    __syncthreads();

    float my_loc = 0.0f, my_pnll = 0.0f;
    int my_pos = 0;
    if (tid < rows) {
        const int p = p0 + tid;
        const size_t gi = (size_t)b * Pn + p;
        const int w = match[gi];
        const int ti = w >> 1;
        const int ct = (w & 1) ? ((int)lab[ti * 5 + 4] + 1) : 0;
        const float* row = sconf + tid * Cn;  // stride 21 vs 32 banks: 2-way = free
        float m = row[0];
#pragma unroll
        for (int j = 1; j < Cn; ++j) m = fmaxf(m, row[j]);
        float s = 0.0f;
#pragma unroll
        for (int j = 0; j < Cn; ++j) s += expf(row[j] - m);
        const float nll = logf(s) + m - row[ct];
        if (ct > 0) {
            lc[gi] = 0.0f;  // mining score zeroed at positives
            my_pos = 1;
            my_pnll = nll;
            const float4 pr = reinterpret_cast<const float4*>(priors)[p];
            const float gx0 = lab[ti * 5 + 0], gy0 = lab[ti * 5 + 1];
            const float gx1 = lab[ti * 5 + 2], gy1 = lab[ti * 5 + 3];
            const float tx = ((gx0 + gx1) * 0.5f - pr.x) / (0.1f * pr.z);
            const float ty = ((gy0 + gy1) * 0.5f - pr.y) / (0.1f * pr.w);
            const float tw = logf((gx1 - gx0) / pr.z) / 0.2f;
            const float th = logf((gy1 - gy0) / pr.w) / 0.2f;
            const float4 l = reinterpret_cast<const float4*>(loc)[gi];
            float d;
            d = fabsf(l.x - tx); my_loc += (d < 1.0f) ? 0.5f * d * d : d - 0.5f;
            d = fabsf(l.y - ty); my_loc += (d < 1.0f) ? 0.5f * d * d : d - 0.5f;
            d = fabsf(l.z - tw); my_loc += (d < 1.0f) ? 0.5f * d * d : d - 0.5f;
            d = fabsf(l.w - th); my_loc += (d < 1.0f) ? 0.5f * d * d : d - 0.5f;
        } else {
            lc[gi] = nll;
        }
    }
    // block reduce (wave shfl then 4 partials)
    for (int off = 32; off > 0; off >>= 1) {
        my_loc += __shfl_down(my_loc, off);
        my_pnll += __shfl_down(my_pnll, off);
        my_pos += __shfl_down(my_pos, off);
    }
    __shared__ float rl[4], rp[4];
    __shared__ int rc[4];
    const int wid = tid >> 6, lane = tid & 63;
    if (lane == 0) { rl[wid] = my_loc; rp[wid] = my_pnll; rc[wid] = my_pos; }
    __syncthreads();
    if (tid == 0) {
        const float tl = rl[0] + rl[1] + rl[2] + rl[3];
        const float tp = rp[0] + rp[1] + rp[2] + rp[3];
        const int tc = rc[0] + rc[1] + rc[2] + rc[3];
        if (tl != 0.0f) atomicAdd(&acc[0], tl);
        if (tp != 0.0f) atomicAdd(&acc[1], tp);
        if (tc != 0) atomicAdd(&np_b[b], tc);
    }
}

// ---------------------------------------------------------------------------
// K5: hard-negative selection per batch. k-th largest of lc via bisection on
// float bits (lc >= 0 so bits are order-isomorphic). Adds the exact top-k sum
// (ties at boundary contribute (k - count_gt) * v*, index-order irrelevant).
// ---------------------------------------------------------------------------
__global__ __launch_bounds__(256) void k_neg(const float* __restrict__ lc,
                                             const int* __restrict__ np_b,
                                             float* __restrict__ acc) {
    const int b = blockIdx.x;
    const int tid = threadIdx.x;
    __shared__ float s[Pn];  // 34928 B
    for (int i = tid; i < Pn; i += 256) s[i] = lc[(size_t)b * Pn + i];
    __shared__ unsigned bounds[2];
    __shared__ int redc[4];
    __shared__ float redf[4];
    const int k = min(3 * np_b[b], Pn - 1);
    if (tid == 0) { bounds[0] = 0u; bounds[1] = 0x7F800000u; }
    __syncthreads();
    const int wid = tid >> 6, lane = tid & 63;
    while (true) {
        const unsigned lo = bounds[0], hi = bounds[1];
        if (hi - lo <= 1u) break;
        const unsigned mid = lo + ((hi - lo) >> 1);
        const float fm = __uint_as_float(mid);
        int c = 0;
        for (int i = tid; i < Pn; i += 256) c += (s[i] >= fm) ? 1 : 0;
        for (int off = 32; off > 0; off >>= 1) c += __shfl_down(c, off);
        if (lane == 0) redc[wid] = c;
        __syncthreads();
        if (tid == 0) {
            const int total = redc[0] + redc[1] + redc[2] + redc[3];
            if (total >= k) bounds[0] = mid;
            else bounds[1] = mid;
        }
        __syncthreads();
    }
    const float v = __uint_as_float(bounds[0]);  // k-th largest value
    float sm = 0.0f;
    int c = 0;
    for (int i = tid; i < Pn; i += 256) {
        const float x = s[i];
        if (x > v) { sm += x; ++c; }
    }
    for (int off = 32; off > 0; off >>= 1) {
        sm += __shfl_down(sm, off);
        c += __shfl_down(c, off);
    }
    if (lane == 0) { redf[wid] = sm; redc[wid] = c; }
    __syncthreads();
    if (tid == 0) {
        const float smt = redf[0] + redf[1] + redf[2] + redf[3];
        const int ct = redc[0] + redc[1] + redc[2] + redc[3];
        atomicAdd(&acc[1], smt + (float)(k - ct) * v);
    }
}

// ---------------------------------------------------------------------------
// K6: finalize.
// ---------------------------------------------------------------------------
__global__ void k_final(const int* __restrict__ np_b, const float* __restrict__ acc,
                        float* __restrict__ out) {
    int N = 0;
    for (int b = 0; b < Bn; ++b) N += np_b[b];
    const float fN = (float)N;
    out[0] = acc[0] / fN;
    out[1] = acc[1] / fN;
}

extern "C" void kernel_launch(void* const* d_in, const int* in_sizes, int n_in,
                              void* d_out, int out_size, void* d_ws, size_t ws_size,
                              hipStream_t stream) {
    const float* conf = (const float*)d_in[0];
    const float* loc = (const float*)d_in[1];
    const float* priors = (const float*)d_in[2];
    const float* labels = (const float*)d_in[3];
    const int* objc = (const int*)d_in[4];
    float* out = (float*)d_out;

    // workspace layout (4-byte units): acc[2] | np_b[64] | bp[B*NMAX] | match[B*P] | lc[B*P]
    float* acc = (float*)d_ws;
    int* np_b = (int*)d_ws + 2;
    int* bp = (int*)d_ws + 2 + 64;
    int* match = (int*)d_ws + 2 + 64 + Bn * NMAXn;
    float* lc = (float*)d_ws + 2 + 64 + Bn * NMAXn + Bn * Pn;

    hipMemsetAsync(d_ws, 0, (2 + 64) * sizeof(float), stream);

    dim3 g1((Pn + 255) / 256, Bn);
    k_match<<<g1, 256, 0, stream>>>(labels, objc, priors, match);
    k_best_prior<<<Bn * NMAXn, 256, 0, stream>>>(labels, objc, priors, bp);
    k_force<<<1, 64, 0, stream>>>(objc, bp, match);
    k_main<<<g1, 256, 0, stream>>>(conf, loc, priors, labels, match, lc, np_b, acc);
    k_neg<<<Bn, 256, 0, stream>>>(lc, np_b, acc);
    k_final<<<1, 1, 0, stream>>>(np_b, acc, out);
}

// Round 2
// 81.208 us; speedup vs baseline: 1.9063x; 1.9063x over previous
//
#include <hip/hip_runtime.h>
#include <math.h>

#define Bn 64
#define Pn 8732
#define Cn 21
#define NMAXn 50
#define PX 35  // ceil(Pn/256)

// ---------------------------------------------------------------------------
// K1 (fused): blocks [0, Bn*PX) = per-(b,p) best-GT match;
//             blocks [Bn*PX, Bn*PX + Bn*NMAXn) = per-(b,n) best-prior argmax.
// match word: (best_gt_idx << 1) | (best_iou >= 0.5)
// ---------------------------------------------------------------------------
__global__ __launch_bounds__(256) void k_matchbp(const float* __restrict__ labels,
                                                 const int* __restrict__ objc,
                                                 const float* __restrict__ priors,
                                                 int* __restrict__ match,
                                                 int* __restrict__ bp) {
    const int bx = blockIdx.x;
    const int tid = threadIdx.x;
    __shared__ float lab[NMAXn * 5];
    __shared__ int cnt_s;
    __shared__ float sv[256];
    __shared__ int si[256];

    if (bx < Bn * PX) {
        // ---- match role ----
        const int b = bx / PX;
        const int p = (bx % PX) * 256 + tid;
        for (int i = tid; i < NMAXn * 5; i += 256) lab[i] = labels[b * NMAXn * 5 + i];
        if (tid == 0) cnt_s = objc[b];
        __syncthreads();
        if (p >= Pn) return;
        const float4 pr = reinterpret_cast<const float4*>(priors)[p];
        const float px0 = pr.x - 0.5f * pr.z, py0 = pr.y - 0.5f * pr.w;
        const float px1 = pr.x + 0.5f * pr.z, py1 = pr.y + 0.5f * pr.w;
        const float parea = (px1 - px0) * (py1 - py0);
        const int cnt = cnt_s;
        float best = -1.0f;
        int bidx = 0;
        for (int n = 0; n < cnt; ++n) {
            const float gx0 = lab[n * 5 + 0], gy0 = lab[n * 5 + 1];
            const float gx1 = lab[n * 5 + 2], gy1 = lab[n * 5 + 3];
            const float lx = fmaxf(gx0, px0), ly = fmaxf(gy0, py0);
            const float rx = fminf(gx1, px1), ry = fminf(gy1, py1);
            const float w = fmaxf(rx - lx, 0.0f), h = fmaxf(ry - ly, 0.0f);
            const float inter = w * h;
            const float ga = (gx1 - gx0) * (gy1 - gy0);
            const float v = inter / (ga + parea - inter);
            if (v > best) { best = v; bidx = n; }  // strict >: first-occurrence argmax
        }
        match[(size_t)b * Pn + p] = (bidx << 1) | (best >= 0.5f ? 1 : 0);
    } else {
        // ---- best-prior role ----
        const int idx = bx - Bn * PX;
        const int b = idx / NMAXn;
        const int n = idx % NMAXn;
        if (n >= objc[b]) return;  // uniform per block
        const float gx0 = labels[(b * NMAXn + n) * 5 + 0];
        const float gy0 = labels[(b * NMAXn + n) * 5 + 1];
        const float gx1 = labels[(b * NMAXn + n) * 5 + 2];
        const float gy1 = labels[(b * NMAXn + n) * 5 + 3];
        const float ga = (gx1 - gx0) * (gy1 - gy0);
        float best = -1.0f;
        int bidx = 0;
        for (int p = tid; p < Pn; p += 256) {
            const float4 pr = reinterpret_cast<const float4*>(priors)[p];
            const float px0 = pr.x - 0.5f * pr.z, py0 = pr.y - 0.5f * pr.w;
            const float px1 = pr.x + 0.5f * pr.z, py1 = pr.y + 0.5f * pr.w;
            const float lx = fmaxf(gx0, px0), ly = fmaxf(gy0, py0);
            const float rx = fminf(gx1, px1), ry = fminf(gy1, py1);
            const float w = fmaxf(rx - lx, 0.0f), h = fmaxf(ry - ly, 0.0f);
            const float inter = w * h;
            const float pa = (px1 - px0) * (py1 - py0);
            const float v = inter / (ga + pa - inter);
            if (v > best) { best = v; bidx = p; }
        }
        sv[tid] = best;
        si[tid] = bidx;
        __syncthreads();
        for (int s = 128; s > 0; s >>= 1) {
            if (tid < s) {
                const float ov = sv[tid + s];
                const int oi = si[tid + s];
                if (ov > sv[tid] || (ov == sv[tid] && oi < si[tid])) {
                    sv[tid] = ov;
                    si[tid] = oi;
                }
            }
            __syncthreads();
        }
        if (tid == 0) bp[b * NMAXn + n] = si[0];
    }
}

// ---------------------------------------------------------------------------
// K2: forced matches. bp staged to LDS so the per-batch serial loop is
// store-only (no dependent load latency). Last-n-wins preserved.
// ---------------------------------------------------------------------------
__global__ __launch_bounds__(256) void k_force(const int* __restrict__ objc,
                                               const int* __restrict__ bp,
                                               int* __restrict__ match) {
    __shared__ int sbp[Bn * NMAXn];
    const int tid = threadIdx.x;
    for (int i = tid; i < Bn * NMAXn; i += 256) sbp[i] = bp[i];
    __syncthreads();
    if (tid < Bn) {
        const int cnt = objc[tid];
        const size_t base = (size_t)tid * Pn;
        for (int n = 0; n < cnt; ++n) match[base + sbp[tid * NMAXn + n]] = (n << 1) | 1;
    }
}

// ---------------------------------------------------------------------------
// K3: main pass. Per (b,p): lse, nll = lse - logit[ct]; fused smooth-L1 for
// positives; pos-masked mining score lc to ws. Per-block partials via PLAIN
// STORES (no atomics — same-address atomic RMWs across XCDs were the R1 drag).
// ---------------------------------------------------------------------------
__global__ __launch_bounds__(256) void k_main(const float* __restrict__ conf,
                                              const float* __restrict__ loc,
                                              const float* __restrict__ priors,
                                              const float* __restrict__ labels,
                                              const int* __restrict__ match,
                                              float* __restrict__ lc,
                                              float* __restrict__ part_loc,
                                              float* __restrict__ part_nll,
                                              int* __restrict__ part_np) {
    const int b = blockIdx.y;
    const int px = blockIdx.x;
    const int p0 = px * 256;
    const int tid = threadIdx.x;
    const int rows = min(256, Pn - p0);
    const int p = p0 + ((tid < rows) ? tid : 0);
    const size_t gi = (size_t)b * Pn + p;
    const int w = match[gi];  // issued before staging: latency hides under it

    __shared__ float sconf[256 * Cn];
    __shared__ float lab[NMAXn * 5];
    const float4* src = reinterpret_cast<const float4*>(conf + ((size_t)b * Pn + p0) * Cn);
    const int n4 = rows * Cn / 4;  // rows*21 divisible by 4 for rows in {256,28}
    for (int i = tid; i < n4; i += 256) reinterpret_cast<float4*>(sconf)[i] = src[i];
    for (int i = tid; i < NMAXn * 5; i += 256) lab[i] = labels[b * NMAXn * 5 + i];
    __syncthreads();

    float my_loc = 0.0f, my_nll = 0.0f;
    int my_np = 0;
    if (tid < rows) {
        const int ti = w >> 1;
        const int ct = (w & 1) ? ((int)lab[ti * 5 + 4] + 1) : 0;
        const float* row = sconf + tid * Cn;  // stride 21: odd -> conflict-benign
        float m = row[0];
#pragma unroll
        for (int j = 1; j < Cn; ++j) m = fmaxf(m, row[j]);
        float s2 = 0.0f;
#pragma unroll
        for (int j = 0; j < Cn; ++j) s2 += __expf(row[j] - m);
        const float nll = __logf(s2) + m - row[ct];
        if (ct > 0) {
            lc[gi] = 0.0f;
            my_np = 1;
            my_nll = nll;
            const float4 pr = reinterpret_cast<const float4*>(priors)[p];
            const float gx0 = lab[ti * 5 + 0], gy0 = lab[ti * 5 + 1];
            const float gx1 = lab[ti * 5 + 2], gy1 = lab[ti * 5 + 3];
            const float tx = ((gx0 + gx1) * 0.5f - pr.x) / (0.1f * pr.z);
            const float ty = ((gy0 + gy1) * 0.5f - pr.y) / (0.1f * pr.w);
            const float tw = __logf((gx1 - gx0) / pr.z) * 5.0f;  // /0.2
            const float th = __logf((gy1 - gy0) / pr.w) * 5.0f;
            const float4 l = reinterpret_cast<const float4*>(loc)[gi];
            float d;
            d = fabsf(l.x - tx); my_loc += (d < 1.0f) ? 0.5f * d * d : d - 0.5f;
            d = fabsf(l.y - ty); my_loc += (d < 1.0f) ? 0.5f * d * d : d - 0.5f;
            d = fabsf(l.z - tw); my_loc += (d < 1.0f) ? 0.5f * d * d : d - 0.5f;
            d = fabsf(l.w - th); my_loc += (d < 1.0f) ? 0.5f * d * d : d - 0.5f;
        } else {
            lc[gi] = nll;
        }
    }
    for (int off = 32; off > 0; off >>= 1) {
        my_loc += __shfl_down(my_loc, off);
        my_nll += __shfl_down(my_nll, off);
        my_np += __shfl_down(my_np, off);
    }
    __shared__ float rl[4], rn[4];
    __shared__ int rp[4];
    const int wid = tid >> 6, lane = tid & 63;
    if (lane == 0) { rl[wid] = my_loc; rn[wid] = my_nll; rp[wid] = my_np; }
    __syncthreads();
    if (tid == 0) {
        const int g = b * PX + px;
        part_loc[g] = rl[0] + rl[1] + rl[2] + rl[3];
        part_nll[g] = rn[0] + rn[1] + rn[2] + rn[3];
        part_np[g] = rp[0] + rp[1] + rp[2] + rp[3];
    }
}

// ---------------------------------------------------------------------------
// K4: per-batch hard-negative top-k sum. k-th largest via 31-step bisection on
// float bits (lc >= 0). 512 threads, float4 LDS scans. num_pos summed from
// partials in-kernel. Result to negsum[b] (plain store).
// ---------------------------------------------------------------------------
__global__ __launch_bounds__(512) void k_neg(const float* __restrict__ lc,
                                             const int* __restrict__ part_np,
                                             float* __restrict__ negsum) {
    const int b = blockIdx.x;
    const int tid = threadIdx.x;
    __shared__ float s[Pn];  // 34928 B
    __shared__ int np_sh;
    __shared__ unsigned bounds[2];
    __shared__ int redc[8];
    __shared__ float redf[8];
    const float4* src = reinterpret_cast<const float4*>(lc + (size_t)b * Pn);
    for (int i = tid; i < Pn / 4; i += 512) reinterpret_cast<float4*>(s)[i] = src[i];
    int npl = (tid < PX) ? part_np[b * PX + tid] : 0;
    for (int off = 32; off > 0; off >>= 1) npl += __shfl_down(npl, off);
    if (tid == 0) { np_sh = npl; bounds[0] = 0u; bounds[1] = 0x7F800000u; }
    __syncthreads();
    const int k = min(3 * np_sh, Pn - 1);
    const int wid = tid >> 6, lane = tid & 63;
    while (true) {
        const unsigned lo = bounds[0], hi = bounds[1];
        if (hi - lo <= 1u) break;
        const unsigned mid = lo + ((hi - lo) >> 1);
        const float fm = __uint_as_float(mid);
        int c = 0;
        for (int i = tid; i < Pn / 4; i += 512) {
            const float4 v = reinterpret_cast<const float4*>(s)[i];
            c += (v.x >= fm) + (v.y >= fm) + (v.z >= fm) + (v.w >= fm);
        }
        for (int off = 32; off > 0; off >>= 1) c += __shfl_down(c, off);
        if (lane == 0) redc[wid] = c;
        __syncthreads();
        if (tid == 0) {
            int t = 0;
#pragma unroll
            for (int i = 0; i < 8; ++i) t += redc[i];
            if (t >= k) bounds[0] = mid;
            else bounds[1] = mid;
        }
        __syncthreads();
    }
    const float v = __uint_as_float(bounds[0]);
    float sm = 0.0f;
    int c = 0;
    for (int i = tid; i < Pn / 4; i += 512) {
        const float4 q = reinterpret_cast<const float4*>(s)[i];
        if (q.x > v) { sm += q.x; ++c; }
        if (q.y > v) { sm += q.y; ++c; }
        if (q.z > v) { sm += q.z; ++c; }
        if (q.w > v) { sm += q.w; ++c; }
    }
    for (int off = 32; off > 0; off >>= 1) {
        sm += __shfl_down(sm, off);
        c += __shfl_down(c, off);
    }
    if (lane == 0) { redf[wid] = sm; redc[wid] = c; }
    __syncthreads();
    if (tid == 0) {
        float st = 0.0f;
        int ct = 0;
#pragma unroll
        for (int i = 0; i < 8; ++i) { st += redf[i]; ct += redc[i]; }
        negsum[b] = st + (float)(k - ct) * v;  // exact tie handling at boundary
    }
}

// ---------------------------------------------------------------------------
// K5: final reduce of all partials. One 256-thread block.
// ---------------------------------------------------------------------------
__global__ __launch_bounds__(256) void k_final(const float* __restrict__ part_loc,
                                               const float* __restrict__ part_nll,
                                               const int* __restrict__ part_np,
                                               const float* __restrict__ negsum,
                                               float* __restrict__ out) {
    const int tid = threadIdx.x;
    float sl = 0.0f, sn = 0.0f;
    int np = 0;
    for (int i = tid; i < Bn * PX; i += 256) {
        sl += part_loc[i];
        sn += part_nll[i];
        np += part_np[i];
    }
    if (tid < Bn) sn += negsum[tid];
    for (int off = 32; off > 0; off >>= 1) {
        sl += __shfl_down(sl, off);
        sn += __shfl_down(sn, off);
        np += __shfl_down(np, off);
    }
    __shared__ float rl[4], rn[4];
    __shared__ int rp[4];
    const int wid = tid >> 6, lane = tid & 63;
    if (lane == 0) { rl[wid] = sl; rn[wid] = sn; rp[wid] = np; }
    __syncthreads();
    if (tid == 0) {
        const float fN = (float)(rp[0] + rp[1] + rp[2] + rp[3]);
        out[0] = (rl[0] + rl[1] + rl[2] + rl[3]) / fN;
        out[1] = (rn[0] + rn[1] + rn[2] + rn[3]) / fN;
    }
}

extern "C" void kernel_launch(void* const* d_in, const int* in_sizes, int n_in,
                              void* d_out, int out_size, void* d_ws, size_t ws_size,
                              hipStream_t stream) {
    const float* conf = (const float*)d_in[0];
    const float* loc = (const float*)d_in[1];
    const float* priors = (const float*)d_in[2];
    const float* labels = (const float*)d_in[3];
    const int* objc = (const int*)d_in[4];
    float* out = (float*)d_out;

    // ws layout (4B units): part_loc[2240] | part_nll[2240] | part_np[2240] |
    //                       negsum[64] | bp[3200] | match[B*P] | lc[B*P]
    float* part_loc = (float*)d_ws;
    float* part_nll = part_loc + Bn * PX;
    int* part_np = (int*)(part_nll + Bn * PX);
    float* negsum = (float*)(part_np + Bn * PX);
    int* bp = (int*)(negsum + Bn);
    int* match = bp + Bn * NMAXn;
    float* lc = (float*)(match + (size_t)Bn * Pn);

    k_matchbp<<<Bn * PX + Bn * NMAXn, 256, 0, stream>>>(labels, objc, priors, match, bp);
    k_force<<<1, 256, 0, stream>>>(objc, bp, match);
    dim3 g(PX, Bn);
    k_main<<<g, 256, 0, stream>>>(conf, loc, priors, labels, match, lc,
                                  part_loc, part_nll, part_np);
    k_neg<<<Bn, 512, 0, stream>>>(lc, part_np, negsum);
    k_final<<<1, 256, 0, stream>>>(part_loc, part_nll, part_np, negsum, out);
}

// Round 3
// 79.647 us; speedup vs baseline: 1.9436x; 1.0196x over previous
//
#include <hip/hip_runtime.h>
#include <math.h>

#define Bn 64
#define Pn 8732
#define Cn 21
#define NMAXn 50
#define PX 35  // ceil(Pn/256)

// ---------------------------------------------------------------------------
// K1 (fused): blocks [0, Bn*PX) = per-(b,p) best-GT match;
//             blocks [Bn*PX, Bn*PX + Bn*NMAXn) = per-(b,n) best-prior argmax.
// match word: (best_gt_idx << 1) | (best_iou >= 0.5)
// ---------------------------------------------------------------------------
__global__ __launch_bounds__(256) void k_matchbp(const float* __restrict__ labels,
                                                 const int* __restrict__ objc,
                                                 const float* __restrict__ priors,
                                                 int* __restrict__ match,
                                                 int* __restrict__ bp) {
    const int bx = blockIdx.x;
    const int tid = threadIdx.x;
    __shared__ float lab[NMAXn * 5];
    __shared__ int cnt_s;
    __shared__ float sv[256];
    __shared__ int si[256];

    if (bx < Bn * PX) {
        // ---- match role ----
        const int b = bx / PX;
        const int p = (bx % PX) * 256 + tid;
        for (int i = tid; i < NMAXn * 5; i += 256) lab[i] = labels[b * NMAXn * 5 + i];
        if (tid == 0) cnt_s = objc[b];
        __syncthreads();
        if (p >= Pn) return;
        const float4 pr = reinterpret_cast<const float4*>(priors)[p];
        const float px0 = pr.x - 0.5f * pr.z, py0 = pr.y - 0.5f * pr.w;
        const float px1 = pr.x + 0.5f * pr.z, py1 = pr.y + 0.5f * pr.w;
        const float parea = (px1 - px0) * (py1 - py0);
        const int cnt = cnt_s;
        float best = -1.0f;
        int bidx = 0;
        for (int n = 0; n < cnt; ++n) {
            const float gx0 = lab[n * 5 + 0], gy0 = lab[n * 5 + 1];
            const float gx1 = lab[n * 5 + 2], gy1 = lab[n * 5 + 3];
            const float lx = fmaxf(gx0, px0), ly = fmaxf(gy0, py0);
            const float rx = fminf(gx1, px1), ry = fminf(gy1, py1);
            const float w = fmaxf(rx - lx, 0.0f), h = fmaxf(ry - ly, 0.0f);
            const float inter = w * h;
            const float ga = (gx1 - gx0) * (gy1 - gy0);
            const float v = inter / (ga + parea - inter);
            if (v > best) { best = v; bidx = n; }  // strict >: first-occurrence argmax
        }
        match[(size_t)b * Pn + p] = (bidx << 1) | (best >= 0.5f ? 1 : 0);
    } else {
        // ---- best-prior role ----
        const int idx = bx - Bn * PX;
        const int b = idx / NMAXn;
        const int n = idx % NMAXn;
        if (n >= objc[b]) return;  // uniform per block
        const float gx0 = labels[(b * NMAXn + n) * 5 + 0];
        const float gy0 = labels[(b * NMAXn + n) * 5 + 1];
        const float gx1 = labels[(b * NMAXn + n) * 5 + 2];
        const float gy1 = labels[(b * NMAXn + n) * 5 + 3];
        const float ga = (gx1 - gx0) * (gy1 - gy0);
        float best = -1.0f;
        int bidx = 0;
        for (int p = tid; p < Pn; p += 256) {
            const float4 pr = reinterpret_cast<const float4*>(priors)[p];
            const float px0 = pr.x - 0.5f * pr.z, py0 = pr.y - 0.5f * pr.w;
            const float px1 = pr.x + 0.5f * pr.z, py1 = pr.y + 0.5f * pr.w;
            const float lx = fmaxf(gx0, px0), ly = fmaxf(gy0, py0);
            const float rx = fminf(gx1, px1), ry = fminf(gy1, py1);
            const float w = fmaxf(rx - lx, 0.0f), h = fmaxf(ry - ly, 0.0f);
            const float inter = w * h;
            const float pa = (px1 - px0) * (py1 - py0);
            const float v = inter / (ga + pa - inter);
            if (v > best) { best = v; bidx = p; }
        }
        sv[tid] = best;
        si[tid] = bidx;
        __syncthreads();
        for (int s = 128; s > 0; s >>= 1) {
            if (tid < s) {
                const float ov = sv[tid + s];
                const int oi = si[tid + s];
                if (ov > sv[tid] || (ov == sv[tid] && oi < si[tid])) {
                    sv[tid] = ov;
                    si[tid] = oi;
                }
            }
            __syncthreads();
        }
        if (tid == 0) bp[b * NMAXn + n] = si[0];
    }
}

// ---------------------------------------------------------------------------
// K2: main pass with INLINE forced-match resolution (no separate force kernel,
// no match[] rewrite). Per (b,p): effective target = forced n (ascending scan
// of bp row => last-n-wins, matching scatter order) else IoU match. Then lse,
// nll, fused smooth-L1, pos-masked mining score lc, per-block partials via
// plain stores. Block (0,0) resets the done counter for K3.
// ---------------------------------------------------------------------------
__global__ __launch_bounds__(256) void k_main(const float* __restrict__ conf,
                                              const float* __restrict__ loc,
                                              const float* __restrict__ priors,
                                              const float* __restrict__ labels,
                                              const int* __restrict__ objc,
                                              const int* __restrict__ match,
                                              const int* __restrict__ bp,
                                              float* __restrict__ lc,
                                              float* __restrict__ part_loc,
                                              float* __restrict__ part_nll,
                                              int* __restrict__ part_np,
                                              int* __restrict__ done) {
    const int b = blockIdx.y;
    const int px = blockIdx.x;
    const int p0 = px * 256;
    const int tid = threadIdx.x;
    const int rows = min(256, Pn - p0);
    const int p = p0 + ((tid < rows) ? tid : 0);
    const size_t gi = (size_t)b * Pn + p;
    const int w = match[gi];  // issued before staging: latency hides under it

    if (b == 0 && px == 0 && tid == 0) *done = 0;  // ordered before K3 by kernel boundary

    __shared__ float sconf[256 * Cn];
    __shared__ float lab[NMAXn * 5];
    __shared__ int sbp[NMAXn];
    const float4* src = reinterpret_cast<const float4*>(conf + ((size_t)b * Pn + p0) * Cn);
    const int n4 = rows * Cn / 4;  // rows*21 divisible by 4 for rows in {256,28}
    for (int i = tid; i < n4; i += 256) reinterpret_cast<float4*>(sconf)[i] = src[i];
    for (int i = tid; i < NMAXn * 5; i += 256) lab[i] = labels[b * NMAXn * 5 + i];
    if (tid < NMAXn) sbp[tid] = (tid < objc[b]) ? bp[b * NMAXn + tid] : -1;
    __syncthreads();

    float my_loc = 0.0f, my_nll = 0.0f;
    int my_np = 0;
    if (tid < rows) {
        int ti = w >> 1;
        int fl = w & 1;
#pragma unroll
        for (int n = 0; n < NMAXn; ++n) {  // ascending: last forced n wins
            if (sbp[n] == p) { ti = n; fl = 1; }
        }
        const int ct = fl ? ((int)lab[ti * 5 + 4] + 1) : 0;
        const float* row = sconf + tid * Cn;  // stride 21: odd -> conflict-benign
        float m = row[0];
#pragma unroll
        for (int j = 1; j < Cn; ++j) m = fmaxf(m, row[j]);
        float s2 = 0.0f;
#pragma unroll
        for (int j = 0; j < Cn; ++j) s2 += __expf(row[j] - m);
        const float nll = __logf(s2) + m - row[ct];
        if (ct > 0) {
            lc[gi] = 0.0f;
            my_np = 1;
            my_nll = nll;
            const float4 pr = reinterpret_cast<const float4*>(priors)[p];
            const float gx0 = lab[ti * 5 + 0], gy0 = lab[ti * 5 + 1];
            const float gx1 = lab[ti * 5 + 2], gy1 = lab[ti * 5 + 3];
            const float tx = ((gx0 + gx1) * 0.5f - pr.x) / (0.1f * pr.z);
            const float ty = ((gy0 + gy1) * 0.5f - pr.y) / (0.1f * pr.w);
            const float tw = __logf((gx1 - gx0) / pr.z) * 5.0f;  // /0.2
            const float th = __logf((gy1 - gy0) / pr.w) * 5.0f;
            const float4 l = reinterpret_cast<const float4*>(loc)[gi];
            float d;
            d = fabsf(l.x - tx); my_loc += (d < 1.0f) ? 0.5f * d * d : d - 0.5f;
            d = fabsf(l.y - ty); my_loc += (d < 1.0f) ? 0.5f * d * d : d - 0.5f;
            d = fabsf(l.z - tw); my_loc += (d < 1.0f) ? 0.5f * d * d : d - 0.5f;
            d = fabsf(l.w - th); my_loc += (d < 1.0f) ? 0.5f * d * d : d - 0.5f;
        } else {
            lc[gi] = nll;
        }
    }
    for (int off = 32; off > 0; off >>= 1) {
        my_loc += __shfl_down(my_loc, off);
        my_nll += __shfl_down(my_nll, off);
        my_np += __shfl_down(my_np, off);
    }
    __shared__ float rl[4], rn[4];
    __shared__ int rp[4];
    const int wid = tid >> 6, lane = tid & 63;
    if (lane == 0) { rl[wid] = my_loc; rn[wid] = my_nll; rp[wid] = my_np; }
    __syncthreads();
    if (tid == 0) {
        const int g = b * PX + px;
        part_loc[g] = rl[0] + rl[1] + rl[2] + rl[3];
        part_nll[g] = rn[0] + rn[1] + rn[2] + rn[3];
        part_np[g] = rp[0] + rp[1] + rp[2] + rp[3];
    }
}

// ---------------------------------------------------------------------------
// K3: per-batch hard-negative top-k sum (bisection on float bits, register
// bounds + one sync/iter via per-iteration LDS atomic slots), fused with the
// final reduce: last block to arrive (done counter) reduces all partials and
// writes out[0..1]. Deterministic: final reduce runs in exactly one block
// with fixed loop order.
// ---------------------------------------------------------------------------
__global__ __launch_bounds__(512) void k_neg(const float* __restrict__ lc,
                                             const float* __restrict__ part_loc,
                                             const float* __restrict__ part_nll,
                                             const int* __restrict__ part_np,
                                             float* __restrict__ negsum,
                                             int* __restrict__ done,
                                             float* __restrict__ out) {
    const int b = blockIdx.x;
    const int tid = threadIdx.x;
    __shared__ float s[Pn];  // 34928 B
    __shared__ int cslot[32];
    __shared__ int np_sh;
    __shared__ float redf[8], redf2[8];
    __shared__ int redc[8];
    __shared__ int islast;

    const float4* src = reinterpret_cast<const float4*>(lc + (size_t)b * Pn);
    for (int i = tid; i < Pn / 4; i += 512) reinterpret_cast<float4*>(s)[i] = src[i];
    if (tid < 32) cslot[tid] = 0;
    if (tid < 64) {  // wave 0 reduces num_pos over this batch's PX partials
        int npl = (tid < PX) ? part_np[b * PX + tid] : 0;
        for (int off = 32; off > 0; off >>= 1) npl += __shfl_down(npl, off);
        if (tid == 0) np_sh = npl;
    }
    __syncthreads();
    const int k = min(3 * np_sh, Pn - 1);
    const int wid = tid >> 6, lane = tid & 63;

    unsigned lo = 0u, hi = 0x7F800000u;
#pragma unroll 1
    for (int it = 0; it < 31; ++it) {
        const unsigned mid = lo + ((hi - lo) >> 1);
        const float fm = __uint_as_float(mid);
        int c = 0;
        for (int i = tid; i < Pn / 4; i += 512) {
            const float4 v = reinterpret_cast<const float4*>(s)[i];
            c += (v.x >= fm) + (v.y >= fm) + (v.z >= fm) + (v.w >= fm);
        }
        for (int off = 32; off > 0; off >>= 1) c += __shfl_down(c, off);
        if (lane == 0) atomicAdd(&cslot[it], c);
        __syncthreads();
        const int tot = cslot[it];  // uniform across block
        if (tot >= k) lo = mid;
        else hi = mid;
    }
    const float v = __uint_as_float(lo);  // exact k-th largest value

    float sm = 0.0f;
    int c = 0;
    for (int i = tid; i < Pn / 4; i += 512) {
        const float4 q = reinterpret_cast<const float4*>(s)[i];
        if (q.x > v) { sm += q.x; ++c; }
        if (q.y > v) { sm += q.y; ++c; }
        if (q.z > v) { sm += q.z; ++c; }
        if (q.w > v) { sm += q.w; ++c; }
    }
    for (int off = 32; off > 0; off >>= 1) {
        sm += __shfl_down(sm, off);
        c += __shfl_down(c, off);
    }
    if (lane == 0) { redf[wid] = sm; redc[wid] = c; }
    __syncthreads();
    if (tid == 0) {
        float st = 0.0f;
        int ct = 0;
#pragma unroll
        for (int i = 0; i < 8; ++i) { st += redf[i]; ct += redc[i]; }
        negsum[b] = st + (float)(k - ct) * v;  // exact tie handling at boundary
        __threadfence();
        islast = (atomicAdd(done, 1) == Bn - 1) ? 1 : 0;
    }
    __syncthreads();
    if (!islast) return;
    __threadfence();  // acquire: other blocks' negsum stores precede their fenced atomics

    // ---- fused final reduce (exactly one block runs this) ----
    float sl = 0.0f, sn = 0.0f;
    int np = 0;
    for (int i = tid; i < Bn * PX; i += 512) {
        sl += part_loc[i];
        sn += part_nll[i];
        np += part_np[i];
    }
    if (tid < Bn) sn += negsum[tid];
    for (int off = 32; off > 0; off >>= 1) {
        sl += __shfl_down(sl, off);
        sn += __shfl_down(sn, off);
        np += __shfl_down(np, off);
    }
    if (lane == 0) { redf[wid] = sn; redf2[wid] = sl; redc[wid] = np; }
    __syncthreads();
    if (tid == 0) {
        float tsl = 0.0f, tsn = 0.0f;
        int tnp = 0;
#pragma unroll
        for (int i = 0; i < 8; ++i) { tsl += redf2[i]; tsn += redf[i]; tnp += redc[i]; }
        const float fN = (float)tnp;
        out[0] = tsl / fN;
        out[1] = tsn / fN;
    }
}

extern "C" void kernel_launch(void* const* d_in, const int* in_sizes, int n_in,
                              void* d_out, int out_size, void* d_ws, size_t ws_size,
                              hipStream_t stream) {
    const float* conf = (const float*)d_in[0];
    const float* loc = (const float*)d_in[1];
    const float* priors = (const float*)d_in[2];
    const float* labels = (const float*)d_in[3];
    const int* objc = (const int*)d_in[4];
    float* out = (float*)d_out;

    // ws layout (4B units): part_loc[2240] | part_nll[2240] | part_np[2240] |
    //                       negsum[64] | bp[3200] | match[B*P] | lc[B*P] | done[1]
    float* part_loc = (float*)d_ws;
    float* part_nll = part_loc + Bn * PX;
    int* part_np = (int*)(part_nll + Bn * PX);
    float* negsum = (float*)(part_np + Bn * PX);
    int* bp = (int*)(negsum + Bn);
    int* match = bp + Bn * NMAXn;
    float* lc = (float*)(match + (size_t)Bn * Pn);
    int* done = (int*)(lc + (size_t)Bn * Pn);

    k_matchbp<<<Bn * PX + Bn * NMAXn, 256, 0, stream>>>(labels, objc, priors, match, bp);
    dim3 g(PX, Bn);
    k_main<<<g, 256, 0, stream>>>(conf, loc, priors, labels, objc, match, bp, lc,
                                  part_loc, part_nll, part_np, done);
    k_neg<<<Bn, 512, 0, stream>>>(lc, part_loc, part_nll, part_np, negsum, done, out);
}